// Round 11
// baseline (173.861 us; speedup 1.0000x reference)
//
#include <hip/hip_runtime.h>

#define N_EMB 16384
#define DIM 128
#define NSPLIT 8
#define CPS (N_EMB / NSPLIT) /* 2048 cols per split */
#define BN 128
#define NCT (CPS / BN) /* 16 column tiles per block */
#define NLAB 64

typedef __bf16 bf16x8 __attribute__((ext_vector_type(8)));
typedef float f32x4 __attribute__((ext_vector_type(4)));
typedef unsigned short us8 __attribute__((ext_vector_type(8)));
typedef unsigned int u32;

#define SCALE 2.8853900817779268f /* (1/T)*log2(e), T=0.5 */
#define LN2 0.6931471805599453f

__device__ inline float fast_exp2(float x) {
#if __has_builtin(__builtin_amdgcn_exp2f)
  return __builtin_amdgcn_exp2f(x);
#else
  return exp2f(x);
#endif
}
__device__ inline float fast_log2(float x) {
#if __has_builtin(__builtin_amdgcn_logf)
  return __builtin_amdgcn_logf(x);
#else
  return log2f(x);
#endif
}

// fp32 -> bf16 RNE (finite inputs)
__device__ inline unsigned short f2bf(float f) {
  unsigned int u = __float_as_uint(f);
  u += 0x7fffu + ((u >> 16) & 1u);
  return (unsigned short)(u >> 16);
}

// global->LDS DMA, 16 B per lane. LDS dest = wave-uniform base + lane*16.
__device__ inline void gll16(const unsigned short* g, unsigned short* l) {
  __builtin_amdgcn_global_load_lds(
      (const __attribute__((address_space(1))) u32*)g,
      (__attribute__((address_space(3))) u32*)l, 16, 0, 0);
}

// ---------------------------------------------------------------------------
// Counting sort by label, 16-wave single block (r2-proven). Also emits
// labs[i] = label of sorted row i (for the pos-window mask compares).
// ---------------------------------------------------------------------------
__global__ __launch_bounds__(1024) void perm_kernel(
    const int* __restrict__ labels, int* __restrict__ perm,
    int* __restrict__ gstart, int* __restrict__ labs) {
  __shared__ int whist[16][NLAB];
  __shared__ int htot[NLAB];
  const int tid = threadIdx.x;
  const int w = tid >> 6, lane = tid & 63;
  whist[w][lane] = 0;
  __syncthreads();
  const int base_i = w * 1024;
  int mylab[16];
#pragma unroll
  for (int k = 0; k < 16; ++k) {
    int lab = labels[base_i + k * 64 + lane];
    mylab[k] = lab;
    atomicAdd(&whist[w][lab], 1);
  }
  __syncthreads();
  if (tid < NLAB) {
    int s = 0;
#pragma unroll
    for (int ww = 0; ww < 16; ++ww) {
      int t = whist[ww][tid];
      whist[ww][tid] = s;
      s += t;
    }
    htot[tid] = s;
  }
  __syncthreads();
  if (tid == 0) {
    int s = 0;
    for (int l = 0; l < NLAB; ++l) {
      int t = htot[l];
      gstart[l] = s;
      htot[l] = s;
      s += t;
    }
    gstart[NLAB] = s;
  }
  __syncthreads();
  whist[w][lane] += htot[lane];
  __syncthreads();
#pragma unroll
  for (int k = 0; k < 16; ++k) {
    int lab = mylab[k];
    int pos = atomicAdd(&whist[w][lab], 1);
    perm[pos] = base_i + k * 64 + lane;
    labs[pos] = lab;
  }
}

// ---------------------------------------------------------------------------
// Gather (permuted) + fp32->bf16 convert into fragment-linear layout
// (r1-verified). Fragment (T 16-row tile, ks) at
// (T>>3)*16384 + ((T&7)*4+ks)*512 + lane*8, lane-contiguous 16B/lane.
// ---------------------------------------------------------------------------
__global__ __launch_bounds__(256) void preconv(
    const float* __restrict__ emb, const int* __restrict__ perm,
    unsigned short* __restrict__ eraw) {
  const int tid = threadIdx.x;
  const int tile = blockIdx.x >> 2;
  const int part = blockIdx.x & 3;
  const size_t base = (size_t)tile * (128 * DIM);
#pragma unroll
  for (int i = 0; i < 2; ++i) {
    int G = part * 512 + i * 256 + tid;
    int col16 = G & 15;
    int qd = (G >> 4) & 3;
    int ks = (G >> 6) & 3;
    int tc = G >> 8;
    int srow = perm[tile * 128 + tc * 16 + col16];
    const float* p = emb + (size_t)srow * DIM + ks * 32 + qd * 8;
    float4 a = *reinterpret_cast<const float4*>(p);
    float4 b = *reinterpret_cast<const float4*>(p + 4);
    us8 g;
    g[0] = f2bf(a.x); g[1] = f2bf(a.y); g[2] = f2bf(a.z); g[3] = f2bf(a.w);
    g[4] = f2bf(b.x); g[5] = f2bf(b.y); g[6] = f2bf(b.z); g[7] = f2bf(b.w);
    *reinterpret_cast<us8*>(eraw + base + (size_t)G * 8) = g;
  }
}

// Load one A fragment from raw bf16 and pre-scale by SCALE.
__device__ inline bf16x8 load_scaled(const unsigned short* p) {
  us8 v = *reinterpret_cast<const us8*>(p);
  us8 s;
#pragma unroll
  for (int j = 0; j < 8; ++j)
    s[j] = f2bf(__uint_as_float((u32)v[j] << 16) * SCALE);
  return *reinterpret_cast<bf16x8*>(&s);
}

// ---------------------------------------------------------------------------
// Main kernel, sorted space. grid (128, NSPLIT=8), 128 threads (2 waves).
//  Main loop = r1's measured-78us all-only core verbatim: BN=128 B tile
//  single-buffered via global_load_lds, 2 barriers/ct, 64 rows/wave, A scaled
//  in registers, epilogue = exp2 + add (+ wave-uniform diag-zero branch).
//  Then ONLY split-0 blocks run a pos-window pass: rows are label-sorted, so
//  this block's positives lie in the contiguous column tiles spanned by the
//  <=2 label groups covering rows [r0, r0+127] (~3-6 tiles of 128). Same LDS
//  staging; r0/r10-verified masked epilogue (label cmp + diag-zero). Extra
//  work ~= +4% of total, no separate dispatch, no tail, no label logic in
//  the hot loop (r10 post-mortem: dual epilogue cost +34 us).
// ---------------------------------------------------------------------------
__global__ __launch_bounds__(128) void cl_main(
    const unsigned short* __restrict__ eraw, const int* __restrict__ labs,
    const int* __restrict__ gstart, float* __restrict__ ws_all,
    float* __restrict__ ws_pos) {
  __shared__ unsigned short lds[BN * DIM]; // 32 KB B tile
  const int tid = threadIdx.x;
  const int lane = tid & 63;
  const int w = tid >> 6; // wave 0..1, owns rows [r0+w*64, r0+w*64+64)
  const int col16 = lane & 15;
  const int quad = lane >> 4;
  const int r0 = blockIdx.x * 128;
  const int cs = blockIdx.y;

  // A-frag: lane holds A[m=lane&15][k=quad*8+j] for 16-row tile T, scaled.
  bf16x8 afrag[4][4];
#pragma unroll
  for (int tr = 0; tr < 4; ++tr) {
    const int T = (r0 >> 4) + w * 4 + tr;
    const unsigned short* p = eraw + (size_t)(T >> 3) * (128 * DIM) +
                              ((T & 7) * 4) * 512 + lane * 8;
#pragma unroll
    for (int ks = 0; ks < 4; ++ks) afrag[tr][ks] = load_scaled(p + ks * 512);
  }

  float all_p[16];
#pragma unroll
  for (int t = 0; t < 16; ++t) all_p[t] = 0.f;

  for (int ct = 0; ct < NCT; ++ct) {
    const int c0 = cs * CPS + ct * BN;
    __syncthreads(); // prior compute (or afrag preload) done before overwrite
    {
      const unsigned short* g = eraw + (size_t)(c0 >> 7) * (128 * DIM);
#pragma unroll
      for (int i = 0; i < 16; ++i) {
        int chunk = i * 2 + w;
        gll16(g + chunk * 512 + lane * 8, lds + chunk * 512);
      }
    }
    __syncthreads(); // vmcnt(0) drained -> B tile visible

#pragma unroll
    for (int tc = 0; tc < 8; ++tc) {
      bf16x8 bfr[4];
#pragma unroll
      for (int ks = 0; ks < 4; ++ks)
        bfr[ks] = *reinterpret_cast<const bf16x8*>(lds + (tc * 4 + ks) * 512 +
                                                   lane * 8);
#pragma unroll
      for (int tr = 0; tr < 4; ++tr) {
        f32x4 acc = {0.f, 0.f, 0.f, 0.f};
#pragma unroll
        for (int ks = 0; ks < 4; ++ks)
          acc = __builtin_amdgcn_mfma_f32_16x16x32_bf16(afrag[tr][ks], bfr[ks],
                                                        acc, 0, 0, 0);
        // C/D layout (verified): col = lane&15, row = quad*4 + r
        const bool diag = (c0 + tc * 16) == (r0 + w * 64 + tr * 16);
#pragma unroll
        for (int r = 0; r < 4; ++r) {
          float e = fast_exp2(acc[r]);
          if (diag && (quad * 4 + r) == col16) e = 0.f; // exclude j == i
          all_p[tr * 4 + r] += e;
        }
      }
    }
  }

  // Reduce across the 16 col-lanes sharing each row; store [row][split].
#pragma unroll
  for (int t = 0; t < 16; ++t) {
    float a = all_p[t];
#pragma unroll
    for (int m = 8; m >= 1; m >>= 1) a += __shfl_xor(a, m, 64);
    if (col16 == 0) {
      int row_g = r0 + w * 64 + (t >> 2) * 16 + quad * 4 + (t & 3);
      ws_all[(size_t)row_g * NSPLIT + cs] = a;
    }
  }

  if (cs != 0) return;

  // ---------------- pos-window pass (split-0 blocks only) ----------------
  // Window = column tiles covering the full label groups of rows r0..r0+127.
  int l0 = 0, l1 = 0;
  for (int l = 0; l < NLAB; ++l) {
    int gv = gstart[l];
    if (gv <= r0) l0 = l;
    if (gv <= r0 + 127) l1 = l;
  }
  const int wlo = gstart[l0];
  const int whi = gstart[l1 + 1];
  const int t_lo = wlo >> 7;                       // first 128-col tile
  const int t_hi = (whi + 127) >> 7;               // exclusive
  int labi[16];
  float pos_p[16];
#pragma unroll
  for (int t = 0; t < 16; ++t) {
    labi[t] = labs[r0 + w * 64 + (t >> 2) * 16 + quad * 4 + (t & 3)];
    pos_p[t] = 0.f;
  }

  for (int ct = t_lo; ct < t_hi; ++ct) {
    const int c0 = ct * BN;
    __syncthreads();
    {
      const unsigned short* g = eraw + (size_t)ct * (128 * DIM);
#pragma unroll
      for (int i = 0; i < 16; ++i) {
        int chunk = i * 2 + w;
        gll16(g + chunk * 512 + lane * 8, lds + chunk * 512);
      }
    }
    __syncthreads();

#pragma unroll
    for (int tc = 0; tc < 8; ++tc) {
      bf16x8 bfr[4];
#pragma unroll
      for (int ks = 0; ks < 4; ++ks)
        bfr[ks] = *reinterpret_cast<const bf16x8*>(lds + (tc * 4 + ks) * 512 +
                                                   lane * 8);
      const int labj = labs[c0 + tc * 16 + col16];
#pragma unroll
      for (int tr = 0; tr < 4; ++tr) {
        f32x4 acc = {0.f, 0.f, 0.f, 0.f};
#pragma unroll
        for (int ks = 0; ks < 4; ++ks)
          acc = __builtin_amdgcn_mfma_f32_16x16x32_bf16(afrag[tr][ks], bfr[ks],
                                                        acc, 0, 0, 0);
        const bool diag = (c0 + tc * 16) == (r0 + w * 64 + tr * 16);
#pragma unroll
        for (int r = 0; r < 4; ++r) {
          float e = fast_exp2(acc[r]);
          if (diag && (quad * 4 + r) == col16) e = 0.f; // exclude j == i
          pos_p[tr * 4 + r] += (labi[tr * 4 + r] == labj) ? e : 0.f;
        }
      }
    }
  }

#pragma unroll
  for (int t = 0; t < 16; ++t) {
    float p = pos_p[t];
#pragma unroll
    for (int m = 8; m >= 1; m >>= 1) p += __shfl_xor(p, m, 64);
    if (col16 == 0) {
      int row_g = r0 + w * 64 + (t >> 2) * 16 + quad * 4 + (t & 3);
      ws_pos[row_g] = p;
    }
  }
}

// ---------------------------------------------------------------------------
// Finalize: single block, 1024 threads; [row][split] float4 reads.
// Sorted space throughout (sum over rows is permutation-invariant).
// ---------------------------------------------------------------------------
__global__ __launch_bounds__(1024) void fin(const float* __restrict__ ws_all,
                                            const float* __restrict__ ws_pos,
                                            float* __restrict__ out) {
  __shared__ float s_t[1024];
  __shared__ int s_c[1024];
  const int tid = threadIdx.x;
  float tot = 0.f;
  int cnt = 0;
  for (int row = tid; row < N_EMB; row += 1024) {
    const float4* pa =
        reinterpret_cast<const float4*>(ws_all + (size_t)row * NSPLIT);
    float a = 0.f;
#pragma unroll
    for (int q = 0; q < NSPLIT / 4; ++q) {
      float4 va = pa[q];
      a += va.x + va.y + va.z + va.w;
    }
    const float p = ws_pos[row];
    if (p > 0.f) {
      tot += fast_log2(a) - fast_log2(p);
      cnt++;
    }
  }
  s_t[tid] = tot;
  s_c[tid] = cnt;
  __syncthreads();
  for (int s = 512; s > 0; s >>= 1) {
    if (tid < s) {
      s_t[tid] += s_t[tid + s];
      s_c[tid] += s_c[tid + s];
    }
    __syncthreads();
  }
  if (tid == 0)
    out[0] = (s_c[0] > 0) ? (s_t[0] * LN2 / (float)s_c[0]) : 0.f;
}

extern "C" void kernel_launch(void* const* d_in, const int* in_sizes, int n_in,
                              void* d_out, int out_size, void* d_ws,
                              size_t ws_size, hipStream_t stream) {
  const float* emb = (const float*)d_in[0];
  const int* labels = (const int*)d_in[1];

  unsigned short* eraw = (unsigned short*)d_ws;         // 4 MB bf16 frag-linear
  float* ws_all = (float*)(eraw + (size_t)N_EMB * DIM); // [N][NSPLIT] 512 KB
  float* ws_pos = ws_all + (size_t)N_EMB * NSPLIT;      // [N] 64 KB
  int* perm = (int*)(ws_pos + N_EMB);                   // [N] 64 KB
  int* gstart = perm + N_EMB;                           // [65]
  int* labs = gstart + 72;                              // [N] 64 KB (aligned)

  perm_kernel<<<1, 1024, 0, stream>>>(labels, perm, gstart, labs);
  preconv<<<512, 256, 0, stream>>>(emb, perm, eraw);
  cl_main<<<dim3(128, NSPLIT), 128, 0, stream>>>(eraw, labs, gstart, ws_all,
                                                 ws_pos);
  fin<<<1, 1024, 0, stream>>>(ws_all, ws_pos, (float*)d_out);
}

// Round 12
// 169.839 us; speedup vs baseline: 1.0237x; 1.0237x over previous
//
#include <hip/hip_runtime.h>

#define N_EMB 16384
#define DIM 128
#define NSPLIT 8
#define CPS (N_EMB / NSPLIT) /* 2048 cols per split */
#define BN 128
#define NCT (CPS / BN) /* 16 column tiles per block */
#define NLAB 64

typedef __bf16 bf16x8 __attribute__((ext_vector_type(8)));
typedef float f32x4 __attribute__((ext_vector_type(4)));
typedef unsigned short us8 __attribute__((ext_vector_type(8)));
typedef unsigned int u32;

#define SCALE 2.8853900817779268f /* (1/T)*log2(e), T=0.5 */
#define LN2 0.6931471805599453f

__device__ inline float fast_exp2(float x) {
#if __has_builtin(__builtin_amdgcn_exp2f)
  return __builtin_amdgcn_exp2f(x);
#else
  return exp2f(x);
#endif
}
__device__ inline float fast_log2(float x) {
#if __has_builtin(__builtin_amdgcn_logf)
  return __builtin_amdgcn_logf(x);
#else
  return log2f(x);
#endif
}

// fp32 -> bf16 RNE (finite inputs)
__device__ inline unsigned short f2bf(float f) {
  unsigned int u = __float_as_uint(f);
  u += 0x7fffu + ((u >> 16) & 1u);
  return (unsigned short)(u >> 16);
}

// global->LDS DMA, 16 B per lane. LDS dest = wave-uniform base + lane*16.
__device__ inline void gll16(const unsigned short* g, unsigned short* l) {
  __builtin_amdgcn_global_load_lds(
      (const __attribute__((address_space(1))) u32*)g,
      (__attribute__((address_space(3))) u32*)l, 16, 0, 0);
}

// ---------------------------------------------------------------------------
// Counting sort by label, 16-wave single block (r2-proven). Also emits
// labs[i] = label of sorted row i (for the pos-window mask compares).
// ---------------------------------------------------------------------------
__global__ __launch_bounds__(1024) void perm_kernel(
    const int* __restrict__ labels, int* __restrict__ perm,
    int* __restrict__ gstart, int* __restrict__ labs) {
  __shared__ int whist[16][NLAB];
  __shared__ int htot[NLAB];
  const int tid = threadIdx.x;
  const int w = tid >> 6, lane = tid & 63;
  whist[w][lane] = 0;
  __syncthreads();
  const int base_i = w * 1024;
  int mylab[16];
#pragma unroll
  for (int k = 0; k < 16; ++k) {
    int lab = labels[base_i + k * 64 + lane];
    mylab[k] = lab;
    atomicAdd(&whist[w][lab], 1);
  }
  __syncthreads();
  if (tid < NLAB) {
    int s = 0;
#pragma unroll
    for (int ww = 0; ww < 16; ++ww) {
      int t = whist[ww][tid];
      whist[ww][tid] = s;
      s += t;
    }
    htot[tid] = s;
  }
  __syncthreads();
  if (tid == 0) {
    int s = 0;
    for (int l = 0; l < NLAB; ++l) {
      int t = htot[l];
      gstart[l] = s;
      htot[l] = s;
      s += t;
    }
    gstart[NLAB] = s;
  }
  __syncthreads();
  whist[w][lane] += htot[lane];
  __syncthreads();
#pragma unroll
  for (int k = 0; k < 16; ++k) {
    int lab = mylab[k];
    int pos = atomicAdd(&whist[w][lab], 1);
    perm[pos] = base_i + k * 64 + lane;
    labs[pos] = lab;
  }
}

// ---------------------------------------------------------------------------
// Gather (permuted) + fp32->bf16 convert into fragment-linear layout
// (r1-verified). Fragment (T 16-row tile, ks) at
// (T>>3)*16384 + ((T&7)*4+ks)*512 + lane*8, lane-contiguous 16B/lane.
// ---------------------------------------------------------------------------
__global__ __launch_bounds__(256) void preconv(
    const float* __restrict__ emb, const int* __restrict__ perm,
    unsigned short* __restrict__ eraw) {
  const int tid = threadIdx.x;
  const int tile = blockIdx.x >> 2;
  const int part = blockIdx.x & 3;
  const size_t base = (size_t)tile * (128 * DIM);
#pragma unroll
  for (int i = 0; i < 2; ++i) {
    int G = part * 512 + i * 256 + tid;
    int col16 = G & 15;
    int qd = (G >> 4) & 3;
    int ks = (G >> 6) & 3;
    int tc = G >> 8;
    int srow = perm[tile * 128 + tc * 16 + col16];
    const float* p = emb + (size_t)srow * DIM + ks * 32 + qd * 8;
    float4 a = *reinterpret_cast<const float4*>(p);
    float4 b = *reinterpret_cast<const float4*>(p + 4);
    us8 g;
    g[0] = f2bf(a.x); g[1] = f2bf(a.y); g[2] = f2bf(a.z); g[3] = f2bf(a.w);
    g[4] = f2bf(b.x); g[5] = f2bf(b.y); g[6] = f2bf(b.z); g[7] = f2bf(b.w);
    *reinterpret_cast<us8*>(eraw + base + (size_t)G * 8) = g;
  }
}

// Load one A fragment from raw bf16 and pre-scale by SCALE.
__device__ inline bf16x8 load_scaled(const unsigned short* p) {
  us8 v = *reinterpret_cast<const us8*>(p);
  us8 s;
#pragma unroll
  for (int j = 0; j < 8; ++j)
    s[j] = f2bf(__uint_as_float((u32)v[j] << 16) * SCALE);
  return *reinterpret_cast<bf16x8*>(&s);
}

// ---------------------------------------------------------------------------
// Main kernel, sorted space. grid (128, NSPLIT=8), 128 threads (2 waves).
//  Main loop = r1's measured-78us all-only core verbatim. Then EVERY block
//  runs its share of the pos-window: the window (column tiles covering the
//  label groups of rows r0..r0+127, ~4-6 tiles) is strided across the 8
//  splits (ct = t_lo+cs, +8, ...), so each block adds <=1 tile (~+6% on the
//  critical path -- r11 post-mortem: putting the whole window on split-0
//  made it +31%). Partial pos sums land in ws_pos[row][cs]; fin adds 8.
// ---------------------------------------------------------------------------
__global__ __launch_bounds__(128) void cl_main(
    const unsigned short* __restrict__ eraw, const int* __restrict__ labs,
    const int* __restrict__ gstart, float* __restrict__ ws_all,
    float* __restrict__ ws_pos) {
  __shared__ unsigned short lds[BN * DIM]; // 32 KB B tile
  const int tid = threadIdx.x;
  const int lane = tid & 63;
  const int w = tid >> 6; // wave 0..1, owns rows [r0+w*64, r0+w*64+64)
  const int col16 = lane & 15;
  const int quad = lane >> 4;
  const int r0 = blockIdx.x * 128;
  const int cs = blockIdx.y;

  // A-frag: lane holds A[m=lane&15][k=quad*8+j] for 16-row tile T, scaled.
  bf16x8 afrag[4][4];
#pragma unroll
  for (int tr = 0; tr < 4; ++tr) {
    const int T = (r0 >> 4) + w * 4 + tr;
    const unsigned short* p = eraw + (size_t)(T >> 3) * (128 * DIM) +
                              ((T & 7) * 4) * 512 + lane * 8;
#pragma unroll
    for (int ks = 0; ks < 4; ++ks) afrag[tr][ks] = load_scaled(p + ks * 512);
  }

  float all_p[16];
#pragma unroll
  for (int t = 0; t < 16; ++t) all_p[t] = 0.f;

  for (int ct = 0; ct < NCT; ++ct) {
    const int c0 = cs * CPS + ct * BN;
    __syncthreads(); // prior compute (or afrag preload) done before overwrite
    {
      const unsigned short* g = eraw + (size_t)(c0 >> 7) * (128 * DIM);
#pragma unroll
      for (int i = 0; i < 16; ++i) {
        int chunk = i * 2 + w;
        gll16(g + chunk * 512 + lane * 8, lds + chunk * 512);
      }
    }
    __syncthreads(); // vmcnt(0) drained -> B tile visible

#pragma unroll
    for (int tc = 0; tc < 8; ++tc) {
      bf16x8 bfr[4];
#pragma unroll
      for (int ks = 0; ks < 4; ++ks)
        bfr[ks] = *reinterpret_cast<const bf16x8*>(lds + (tc * 4 + ks) * 512 +
                                                   lane * 8);
#pragma unroll
      for (int tr = 0; tr < 4; ++tr) {
        f32x4 acc = {0.f, 0.f, 0.f, 0.f};
#pragma unroll
        for (int ks = 0; ks < 4; ++ks)
          acc = __builtin_amdgcn_mfma_f32_16x16x32_bf16(afrag[tr][ks], bfr[ks],
                                                        acc, 0, 0, 0);
        // C/D layout (verified): col = lane&15, row = quad*4 + r
        const bool diag = (c0 + tc * 16) == (r0 + w * 64 + tr * 16);
#pragma unroll
        for (int r = 0; r < 4; ++r) {
          float e = fast_exp2(acc[r]);
          if (diag && (quad * 4 + r) == col16) e = 0.f; // exclude j == i
          all_p[tr * 4 + r] += e;
        }
      }
    }
  }

  // Reduce across the 16 col-lanes sharing each row; store [row][split].
#pragma unroll
  for (int t = 0; t < 16; ++t) {
    float a = all_p[t];
#pragma unroll
    for (int m = 8; m >= 1; m >>= 1) a += __shfl_xor(a, m, 64);
    if (col16 == 0) {
      int row_g = r0 + w * 64 + (t >> 2) * 16 + quad * 4 + (t & 3);
      ws_all[(size_t)row_g * NSPLIT + cs] = a;
    }
  }

  // ---------------- pos-window share (every block, <=1-2 tiles) ----------
  // Window = column tiles covering the label groups of rows r0..r0+127.
  int l0 = 0, l1 = 0;
  for (int l = 0; l < NLAB; ++l) {
    int gv = gstart[l];
    if (gv <= r0) l0 = l;
    if (gv <= r0 + 127) l1 = l;
  }
  const int t_lo = gstart[l0] >> 7;              // first 128-col tile
  const int t_hi = (gstart[l1 + 1] + 127) >> 7;  // exclusive

  int labi[16];
  float pos_p[16];
#pragma unroll
  for (int t = 0; t < 16; ++t) {
    labi[t] = labs[r0 + w * 64 + (t >> 2) * 16 + quad * 4 + (t & 3)];
    pos_p[t] = 0.f;
  }

  for (int ct = t_lo + cs; ct < t_hi; ct += NSPLIT) {
    const int c0 = ct * BN;
    __syncthreads();
    {
      const unsigned short* g = eraw + (size_t)ct * (128 * DIM);
#pragma unroll
      for (int i = 0; i < 16; ++i) {
        int chunk = i * 2 + w;
        gll16(g + chunk * 512 + lane * 8, lds + chunk * 512);
      }
    }
    __syncthreads();

#pragma unroll
    for (int tc = 0; tc < 8; ++tc) {
      bf16x8 bfr[4];
#pragma unroll
      for (int ks = 0; ks < 4; ++ks)
        bfr[ks] = *reinterpret_cast<const bf16x8*>(lds + (tc * 4 + ks) * 512 +
                                                   lane * 8);
      const int labj = labs[c0 + tc * 16 + col16];
#pragma unroll
      for (int tr = 0; tr < 4; ++tr) {
        f32x4 acc = {0.f, 0.f, 0.f, 0.f};
#pragma unroll
        for (int ks = 0; ks < 4; ++ks)
          acc = __builtin_amdgcn_mfma_f32_16x16x32_bf16(afrag[tr][ks], bfr[ks],
                                                        acc, 0, 0, 0);
        const bool diag = (c0 + tc * 16) == (r0 + w * 64 + tr * 16);
#pragma unroll
        for (int r = 0; r < 4; ++r) {
          float e = fast_exp2(acc[r]);
          if (diag && (quad * 4 + r) == col16) e = 0.f; // exclude j == i
          pos_p[tr * 4 + r] += (labi[tr * 4 + r] == labj) ? e : 0.f;
        }
      }
    }
  }

#pragma unroll
  for (int t = 0; t < 16; ++t) {
    float p = pos_p[t];
#pragma unroll
    for (int m = 8; m >= 1; m >>= 1) p += __shfl_xor(p, m, 64);
    if (col16 == 0) {
      int row_g = r0 + w * 64 + (t >> 2) * 16 + quad * 4 + (t & 3);
      ws_pos[(size_t)row_g * NSPLIT + cs] = p; // partial (zero if no tiles)
    }
  }
}

// ---------------------------------------------------------------------------
// Finalize: single block, 1024 threads; [row][split] float4 reads for both
// all and pos partials (r10-verified shape).
// ---------------------------------------------------------------------------
__global__ __launch_bounds__(1024) void fin(const float* __restrict__ ws_all,
                                            const float* __restrict__ ws_pos,
                                            float* __restrict__ out) {
  __shared__ float s_t[1024];
  __shared__ int s_c[1024];
  const int tid = threadIdx.x;
  float tot = 0.f;
  int cnt = 0;
  for (int row = tid; row < N_EMB; row += 1024) {
    const float4* pa =
        reinterpret_cast<const float4*>(ws_all + (size_t)row * NSPLIT);
    const float4* pp =
        reinterpret_cast<const float4*>(ws_pos + (size_t)row * NSPLIT);
    float a = 0.f, p = 0.f;
#pragma unroll
    for (int q = 0; q < NSPLIT / 4; ++q) {
      float4 va = pa[q];
      float4 vp = pp[q];
      a += va.x + va.y + va.z + va.w;
      p += vp.x + vp.y + vp.z + vp.w;
    }
    if (p > 0.f) {
      tot += fast_log2(a) - fast_log2(p);
      cnt++;
    }
  }
  s_t[tid] = tot;
  s_c[tid] = cnt;
  __syncthreads();
  for (int s = 512; s > 0; s >>= 1) {
    if (tid < s) {
      s_t[tid] += s_t[tid + s];
      s_c[tid] += s_c[tid + s];
    }
    __syncthreads();
  }
  if (tid == 0)
    out[0] = (s_c[0] > 0) ? (s_t[0] * LN2 / (float)s_c[0]) : 0.f;
}

extern "C" void kernel_launch(void* const* d_in, const int* in_sizes, int n_in,
                              void* d_out, int out_size, void* d_ws,
                              size_t ws_size, hipStream_t stream) {
  const float* emb = (const float*)d_in[0];
  const int* labels = (const int*)d_in[1];

  unsigned short* eraw = (unsigned short*)d_ws;         // 4 MB bf16 frag-linear
  float* ws_all = (float*)(eraw + (size_t)N_EMB * DIM); // [N][NSPLIT] 512 KB
  float* ws_pos = ws_all + (size_t)N_EMB * NSPLIT;      // [N][NSPLIT] 512 KB
  int* perm = (int*)(ws_pos + (size_t)N_EMB * NSPLIT);  // [N] 64 KB
  int* gstart = perm + N_EMB;                           // [65]
  int* labs = gstart + 72;                              // [N] 64 KB (aligned)

  perm_kernel<<<1, 1024, 0, stream>>>(labels, perm, gstart, labs);
  preconv<<<512, 256, 0, stream>>>(emb, perm, eraw);
  cl_main<<<dim3(128, NSPLIT), 128, 0, stream>>>(eraw, labs, gstart, ws_all,
                                                 ws_pos);
  fin<<<1, 1024, 0, stream>>>(ws_all, ws_pos, (float*)d_out);
}